// Round 5
// baseline (465.991 us; speedup 1.0000x reference)
//
#include <hip/hip_runtime.h>
#include <hip/hip_bf16.h>
#include <math.h>

#define NTOK 32768
#define HID  1024
#define NEXP 64
#define H4   256

typedef __attribute__((ext_vector_type(8))) short bf16x8;
typedef __attribute__((ext_vector_type(4))) float f32x4;

static __device__ __forceinline__ ushort f2bf(float x) {
    unsigned u = __float_as_uint(x);
    unsigned r = (u + 0x7FFFu + ((u >> 16) & 1u)) >> 16;   // RNE
    return (ushort)r;
}

// ---------------------------------------------------------------------------
// Kernel 0 (fused prep): blocks 0..255 split w1 into bf16 hi/lo panels;
// blocks 256..319 transpose router_w into RWT[k][64] for logits_gemm.
// ---------------------------------------------------------------------------
__global__ __launch_bounds__(256) void prep_kernel(
    const float* __restrict__ W1, const float* __restrict__ RW,
    ushort* __restrict__ W1h, ushort* __restrict__ W1l,
    float* __restrict__ RWT)
{
    if (blockIdx.x < 256) {
        const int id = blockIdx.x * 256 + threadIdx.x;
        const int c  = id >> 8;
        const int kc = id & 255;
        const int k0 = kc * 4;
        const float4 v = *(const float4*)(W1 + (size_t)c * HID + k0);
        const int p  = k0 >> 5;
        const int kk = k0 & 31;
        const size_t dst = ((size_t)p * H4 + c) * 32 + kk;
        const float xs[4] = {v.x, v.y, v.z, v.w};
        ushort hv[4], lv[4];
#pragma unroll
        for (int j = 0; j < 4; j++) {
            const ushort h = f2bf(xs[j]);
            hv[j] = h;
            lv[j] = f2bf(xs[j] - __uint_as_float(((unsigned)h) << 16));
        }
        *(ushort4*)(W1h + dst) = make_ushort4(hv[0], hv[1], hv[2], hv[3]);
        *(ushort4*)(W1l + dst) = make_ushort4(lv[0], lv[1], lv[2], lv[3]);
    } else {
        // RWT[k][e] = RW[e][k]; one block per expert row
        const int e = blockIdx.x - 256;              // 0..63
        const int k0 = threadIdx.x * 4;              // 0..1020
        const float4 v = *(const float4*)(RW + (size_t)e * HID + k0);
        RWT[(size_t)(k0 + 0) * NEXP + e] = v.x;
        RWT[(size_t)(k0 + 1) * NEXP + e] = v.y;
        RWT[(size_t)(k0 + 2) * NEXP + e] = v.z;
        RWT[(size_t)(k0 + 3) * NEXP + e] = v.w;
    }
}

// ---------------------------------------------------------------------------
// Kernel 1: exact fp32 router-logits GEMM v4 — zero LDS, zero barriers.
// Block 256 thr = 4 waves, 64 tokens (lane = token). Each wave owns 16
// wave-uniform cols; W[k][col..col+15] broadcast-loaded (scalarizable),
// ring-buffered 4 k deep. X streamed global->VGPR one 16-k tile ahead.
// Per k: 16 FMA / lane -> VALU-bound (~27 us floor).
// ---------------------------------------------------------------------------
__global__ __launch_bounds__(256) void logits_gemm(
    const float* __restrict__ X, const float* __restrict__ RWT,
    float* __restrict__ logits)
{
    const int tid  = threadIdx.x;
    const int lane = tid & 63;
    const int wave = tid >> 6;
    const int tok  = blockIdx.x * 64 + lane;
    const int colbase = __builtin_amdgcn_readfirstlane(wave * 16);

    const float* __restrict__ xrow  = X + (size_t)tok * HID;
    const float* __restrict__ wbase = RWT + colbase;

    float acc[16];
#pragma unroll
    for (int c = 0; c < 16; c++) acc[c] = 0.f;

    float4 xr[2][4];   // X: double-buffered 16-k tile
    float4 wr[4][4];   // W: ring, 4 k deep (16 floats per k)

    // preload X tile 0 and W k=0..3
#pragma unroll
    for (int j = 0; j < 4; j++) xr[0][j] = *(const float4*)(xrow + j * 4);
#pragma unroll
    for (int d = 0; d < 4; d++)
#pragma unroll
        for (int j = 0; j < 4; j++)
            wr[d][j] = *(const float4*)(wbase + (size_t)d * NEXP + j * 4);

    int cur = 0;
    // main: tiles k0 = 0..992 (tail tile 1008 peeled)
    for (int k0 = 0; k0 < HID - 16; k0 += 16) {
        // prefetch next X tile (used 16 ks from now)
#pragma unroll
        for (int j = 0; j < 4; j++)
            xr[cur ^ 1][j] = *(const float4*)(xrow + k0 + 16 + j * 4);

#pragma unroll
        for (int kk = 0; kk < 16; kk++) {
            const int k = k0 + kk;
            const int slot = kk & 3;
            const float4 w0 = wr[slot][0], w1 = wr[slot][1];
            const float4 w2 = wr[slot][2], w3 = wr[slot][3];
            // refill slot with k+4 (anti-dep keeps loads after reads)
#pragma unroll
            for (int j = 0; j < 4; j++)
                wr[slot][j] = *(const float4*)(wbase + (size_t)(k + 4) * NEXP + j * 4);

            const float4 xv4 = xr[cur][kk >> 2];
            const float xv = (kk & 3) == 0 ? xv4.x : (kk & 3) == 1 ? xv4.y
                           : (kk & 3) == 2 ? xv4.z : xv4.w;
            acc[ 0] = fmaf(w0.x, xv, acc[ 0]); acc[ 1] = fmaf(w0.y, xv, acc[ 1]);
            acc[ 2] = fmaf(w0.z, xv, acc[ 2]); acc[ 3] = fmaf(w0.w, xv, acc[ 3]);
            acc[ 4] = fmaf(w1.x, xv, acc[ 4]); acc[ 5] = fmaf(w1.y, xv, acc[ 5]);
            acc[ 6] = fmaf(w1.z, xv, acc[ 6]); acc[ 7] = fmaf(w1.w, xv, acc[ 7]);
            acc[ 8] = fmaf(w2.x, xv, acc[ 8]); acc[ 9] = fmaf(w2.y, xv, acc[ 9]);
            acc[10] = fmaf(w2.z, xv, acc[10]); acc[11] = fmaf(w2.w, xv, acc[11]);
            acc[12] = fmaf(w3.x, xv, acc[12]); acc[13] = fmaf(w3.y, xv, acc[13]);
            acc[14] = fmaf(w3.z, xv, acc[14]); acc[15] = fmaf(w3.w, xv, acc[15]);
        }
        cur ^= 1;
    }
    // tail tile k0 = 1008: prefetch only while k+4 < HID (kk < 12)
    {
        const int k0 = HID - 16;
#pragma unroll
        for (int kk = 0; kk < 16; kk++) {
            const int k = k0 + kk;
            const int slot = kk & 3;
            const float4 w0 = wr[slot][0], w1 = wr[slot][1];
            const float4 w2 = wr[slot][2], w3 = wr[slot][3];
            if (kk < 12) {
#pragma unroll
                for (int j = 0; j < 4; j++)
                    wr[slot][j] = *(const float4*)(wbase + (size_t)(k + 4) * NEXP + j * 4);
            }
            const float4 xv4 = xr[cur][kk >> 2];
            const float xv = (kk & 3) == 0 ? xv4.x : (kk & 3) == 1 ? xv4.y
                           : (kk & 3) == 2 ? xv4.z : xv4.w;
            acc[ 0] = fmaf(w0.x, xv, acc[ 0]); acc[ 1] = fmaf(w0.y, xv, acc[ 1]);
            acc[ 2] = fmaf(w0.z, xv, acc[ 2]); acc[ 3] = fmaf(w0.w, xv, acc[ 3]);
            acc[ 4] = fmaf(w1.x, xv, acc[ 4]); acc[ 5] = fmaf(w1.y, xv, acc[ 5]);
            acc[ 6] = fmaf(w1.z, xv, acc[ 6]); acc[ 7] = fmaf(w1.w, xv, acc[ 7]);
            acc[ 8] = fmaf(w2.x, xv, acc[ 8]); acc[ 9] = fmaf(w2.y, xv, acc[ 9]);
            acc[10] = fmaf(w2.z, xv, acc[10]); acc[11] = fmaf(w2.w, xv, acc[11]);
            acc[12] = fmaf(w3.x, xv, acc[12]); acc[13] = fmaf(w3.y, xv, acc[13]);
            acc[14] = fmaf(w3.z, xv, acc[14]); acc[15] = fmaf(w3.w, xv, acc[15]);
        }
    }

#pragma unroll
    for (int j = 0; j < 4; j++) {
        float4 v = {acc[j * 4], acc[j * 4 + 1], acc[j * 4 + 2], acc[j * 4 + 3]};
        *(float4*)(logits + (size_t)tok * NEXP + colbase + j * 4) = v;
    }
}

// ---------------------------------------------------------------------------
// Kernel 2: complexity predictor via split-bf16 MFMA (unchanged, proven).
// ---------------------------------------------------------------------------
__global__ __launch_bounds__(256) void pred_mfma(
    const float* __restrict__ X,
    const ushort* __restrict__ W1h, const ushort* __restrict__ W1l,
    const float* __restrict__ B1, const float* __restrict__ W2,
    float* __restrict__ s2ws)
{
    __shared__ ushort Ah[4096];
    __shared__ ushort Al[4096];
    __shared__ ushort Bh[4096];
    __shared__ ushort Bl[4096];

    const int tid  = threadIdx.x;
    const int lane = tid & 63;
    const int wave = tid >> 6;
    const int wr = wave >> 1, wc = wave & 1;
    const int quad = lane >> 4, l15 = lane & 15;
    const int tok0 = blockIdx.x * 128;
    const int cb   = blockIdx.y;

    f32x4 acc[4][4];
#pragma unroll
    for (int fi = 0; fi < 4; fi++)
#pragma unroll
        for (int fj = 0; fj < 4; fj++) acc[fi][fj] = (f32x4){0.f, 0.f, 0.f, 0.f};

    float w2r[4], b1r[4];
#pragma unroll
    for (int f = 0; f < 4; f++) {
        const int col = cb * 128 + wc * 64 + f * 16 + l15;
        w2r[f] = W2[col];
        b1r[f] = B1[col];
    }

    for (int p = 0; p < 32; ++p) {
        const int k0 = p * 32;
        __syncthreads();

        {
            const size_t tile = ((size_t)p * H4 + cb * 128) * 32;
#pragma unroll
            for (int i = 0; i < 2; ++i) {
                const int j = i * 256 + tid;
                __builtin_amdgcn_global_load_lds(
                    (const __attribute__((address_space(1))) void*)(W1h + tile + (size_t)j * 8),
                    (__attribute__((address_space(3))) void*)((char*)Bh + (size_t)j * 16),
                    16, 0, 0);
                __builtin_amdgcn_global_load_lds(
                    (const __attribute__((address_space(1))) void*)(W1l + tile + (size_t)j * 8),
                    (__attribute__((address_space(3))) void*)((char*)Bl + (size_t)j * 16),
                    16, 0, 0);
            }
        }

#pragma unroll
        for (int it = 0; it < 4; ++it) {
            const int idx = it * 256 + tid;
            const int t   = idx >> 3;
            const int kc  = idx & 7;
            const float4 v = *(const float4*)(X + (size_t)(tok0 + t) * HID + k0 + kc * 4);
            const float xs[4] = {v.x, v.y, v.z, v.w};
            ushort hv[4], lv[4];
#pragma unroll
            for (int j = 0; j < 4; j++) {
                const ushort h = f2bf(xs[j]);
                hv[j] = h;
                lv[j] = f2bf(xs[j] - __uint_as_float(((unsigned)h) << 16));
            }
            const int a = t * 32 + kc * 4;
            *(ushort4*)&Ah[a] = make_ushort4(hv[0], hv[1], hv[2], hv[3]);
            *(ushort4*)&Al[a] = make_ushort4(lv[0], lv[1], lv[2], lv[3]);
        }
        __syncthreads();

        bf16x8 a_h[4], a_l[4], b_h[4], b_l[4];
#pragma unroll
        for (int f = 0; f < 4; ++f) {
            const int ra = (wr * 64 + f * 16 + l15) * 32 + quad * 8;
            const int rb = (wc * 64 + f * 16 + l15) * 32 + quad * 8;
            a_h[f] = *(const bf16x8*)&Ah[ra];
            a_l[f] = *(const bf16x8*)&Al[ra];
            b_h[f] = *(const bf16x8*)&Bh[rb];
            b_l[f] = *(const bf16x8*)&Bl[rb];
        }
#pragma unroll
        for (int fi = 0; fi < 4; ++fi)
#pragma unroll
            for (int fj = 0; fj < 4; ++fj) {
                acc[fi][fj] = __builtin_amdgcn_mfma_f32_16x16x32_bf16(a_h[fi], b_h[fj], acc[fi][fj], 0, 0, 0);
                acc[fi][fj] = __builtin_amdgcn_mfma_f32_16x16x32_bf16(a_l[fi], b_h[fj], acc[fi][fj], 0, 0, 0);
                acc[fi][fj] = __builtin_amdgcn_mfma_f32_16x16x32_bf16(a_h[fi], b_l[fj], acc[fi][fj], 0, 0, 0);
            }
    }

#pragma unroll
    for (int fi = 0; fi < 4; ++fi) {
#pragma unroll
        for (int r = 0; r < 4; ++r) {
            float s = 0.f;
#pragma unroll
            for (int fj = 0; fj < 4; ++fj) {
                const float hval = acc[fi][fj][r] + b1r[fj];
                s = fmaf(w2r[fj], fmaxf(hval, 0.f), s);
            }
            s += __shfl_xor(s, 1);
            s += __shfl_xor(s, 2);
            s += __shfl_xor(s, 4);
            s += __shfl_xor(s, 8);
            if (l15 == 0)
                atomicAdd(&s2ws[tok0 + wr * 64 + fi * 16 + quad * 4 + r], s);
        }
    }
}

// ---------------------------------------------------------------------------
// Kernel 3: per-token routing (unchanged, proven fast)
// ---------------------------------------------------------------------------
__global__ __launch_bounds__(64) void route_kernel(
    const float* __restrict__ logits, const float* __restrict__ s2ws,
    const float* __restrict__ B2, float* __restrict__ sel,
    float* __restrict__ wts, float* __restrict__ load_sum,
    float* __restrict__ ent_sum)
{
    const int lane = threadIdx.x;
    const int tok  = blockIdx.x * 64 + lane;

    float r[64];
    const float* lr = logits + (size_t)tok * NEXP;
#pragma unroll
    for (int e4 = 0; e4 < 16; e4++) {
        float4 v = *(const float4*)(lr + e4 * 4);
        r[e4 * 4 + 0] = v.x; r[e4 * 4 + 1] = v.y;
        r[e4 * 4 + 2] = v.z; r[e4 * 4 + 3] = v.w;
    }

    float v0 = -1e30f, v1 = -1e30f, v2 = -1e30f, v3 = -1e30f;
    int   i0 = 0, i1 = 0, i2 = 0, i3 = 0;
#pragma unroll
    for (int e = 0; e < 64; e++) {
        const float v = r[e];
        if (v > v3) {
            if (v > v2) {
                if (v > v1) {
                    if (v > v0) { v3=v2;i3=i2; v2=v1;i2=i1; v1=v0;i1=i0; v0=v;i0=e; }
                    else        { v3=v2;i3=i2; v2=v1;i2=i1; v1=v;i1=e; }
                } else          { v3=v2;i3=i2; v2=v;i2=e; }
            } else              { v3=v;i3=e; }
        }
    }

    const float s2 = s2ws[tok] + B2[0];
    const bool k4 = (s2 > 0.f);

    float w0, w1v, w2v, w3v;
    int   s1i, s2i, s3i;
    if (k4) {
        const float e0 = expf(v0 - v0), e1 = expf(v1 - v0);
        const float e2 = expf(v2 - v0), e3 = expf(v3 - v0);
        const float inv4 = 1.f / (e0 + e1 + e2 + e3);
        w0 = e0 * inv4; w1v = e1 * inv4; w2v = e2 * inv4; w3v = e3 * inv4;
        s1i = i1; s2i = i2; s3i = i3;
    } else {
        w0 = 1.f; w1v = 0.f; w2v = 0.f; w3v = 0.f;
        s1i = 0; s2i = 0; s3i = 0;
    }
    {
        float4 sv = {(float)i0, (float)s1i, (float)s2i, (float)s3i};
        float4 wv = {w0, w1v, w2v, w3v};
        *(float4*)(sel + (size_t)tok * 4) = sv;
        *(float4*)(wts + (size_t)tok * 4) = wv;
    }

    const float mx = v0;
    float S = 0.f, pz = 0.f;
#pragma unroll
    for (int e = 0; e < 64; e++) {
        const float z = r[e] - mx;
        const float t = expf(z);
        S += t; pz = fmaf(t, z, pz);
        r[e] = t;
    }
    const float inv = 1.f / S;
    float ent = logf(S) - pz * inv;

    float myload = 0.f;
#pragma unroll
    for (int e = 0; e < 64; e++) {
        float s = r[e] * inv;
        s += __shfl_xor(s, 1);
        s += __shfl_xor(s, 2);
        s += __shfl_xor(s, 4);
        s += __shfl_xor(s, 8);
        s += __shfl_xor(s, 16);
        s += __shfl_xor(s, 32);
        if (lane == e) myload = s;
    }
    atomicAdd(&load_sum[lane], myload);

    ent += __shfl_xor(ent, 1);
    ent += __shfl_xor(ent, 2);
    ent += __shfl_xor(ent, 4);
    ent += __shfl_xor(ent, 8);
    ent += __shfl_xor(ent, 16);
    ent += __shfl_xor(ent, 32);
    if (lane == 0) atomicAdd(ent_sum, ent);
}

__global__ void finalize_kernel(const float* __restrict__ load_sum,
                                const float* __restrict__ ent_sum,
                                float* __restrict__ out_scal)
{
    const int lane = threadIdx.x;
    const float le = load_sum[lane] * (1.f / (float)NTOK);
    float s = le;
#pragma unroll
    for (int o = 32; o >= 1; o >>= 1) s += __shfl_xor(s, o);
    const float mean = s * (1.f / 64.f);
    const float d = le - mean;
    float v = d * d;
#pragma unroll
    for (int o = 32; o >= 1; o >>= 1) v += __shfl_xor(v, o);
    if (lane == 0) {
        out_scal[0] = v * (1.f / 63.f);
        out_scal[1] = ent_sum[0] * (1.f / (float)NTOK);
    }
}

extern "C" void kernel_launch(void* const* d_in, const int* in_sizes, int n_in,
                              void* d_out, int out_size, void* d_ws, size_t ws_size,
                              hipStream_t stream) {
    const float* X  = (const float*)d_in[0];
    const float* RW = (const float*)d_in[1];
    const float* W1 = (const float*)d_in[2];
    const float* B1 = (const float*)d_in[3];
    const float* W2 = (const float*)d_in[4];
    const float* B2 = (const float*)d_in[5];

    float* out    = (float*)d_out;
    float* logits = out;
    float* sel    = out + (size_t)NTOK * NEXP;
    float* wts    = sel + (size_t)NTOK * 4;
    float* scal   = wts + (size_t)NTOK * 4;

    float* s2ws     = (float*)d_ws;                       // [32768]
    float* load_sum = s2ws + NTOK;                        // [64]
    float* ent_sum  = load_sum + 64;                      // [1]
    ushort* W1h = (ushort*)(s2ws + NTOK + 256);           // 512 KB
    ushort* W1l = W1h + (size_t)H4 * HID;                 // 512 KB
    float*  RWT = (float*)(W1l + (size_t)H4 * HID);       // 256 KB, [1024][64]

    hipMemsetAsync(d_ws, 0, (size_t)(NTOK + 65) * sizeof(float), stream);

    prep_kernel<<<320, 256, 0, stream>>>(W1, RW, W1h, W1l, RWT);
    logits_gemm<<<NTOK / 64, 256, 0, stream>>>(X, RWT, logits);
    pred_mfma<<<dim3(NTOK / 128, 2), 256, 0, stream>>>(X, W1h, W1l, B1, W2, s2ws);
    route_kernel<<<NTOK / 64, 64, 0, stream>>>(logits, s2ws, B2, sel, wts, load_sum, ent_sum);
    finalize_kernel<<<1, 64, 0, stream>>>(load_sum, ent_sum, scal);
}

// Round 6
// 342.469 us; speedup vs baseline: 1.3607x; 1.3607x over previous
//
#include <hip/hip_runtime.h>
#include <hip/hip_bf16.h>
#include <math.h>

#define NTOK 32768
#define HID  1024
#define NEXP 64
#define H4   256

typedef __attribute__((ext_vector_type(8))) short bf16x8;
typedef __attribute__((ext_vector_type(4))) float f32x4;

static __device__ __forceinline__ ushort f2bf(float x) {
    unsigned u = __float_as_uint(x);
    unsigned r = (u + 0x7FFFu + ((u >> 16) & 1u)) >> 16;   // RNE
    return (ushort)r;
}

// ---------------------------------------------------------------------------
// Kernel 0 (fused prep): blocks 0..255 split w1 into bf16 hi/lo panels;
// blocks 256..319 transpose router_w into RWT[k][64] for logits_gemm.
// ---------------------------------------------------------------------------
__global__ __launch_bounds__(256) void prep_kernel(
    const float* __restrict__ W1, const float* __restrict__ RW,
    ushort* __restrict__ W1h, ushort* __restrict__ W1l,
    float* __restrict__ RWT)
{
    if (blockIdx.x < 256) {
        const int id = blockIdx.x * 256 + threadIdx.x;
        const int c  = id >> 8;
        const int kc = id & 255;
        const int k0 = kc * 4;
        const float4 v = *(const float4*)(W1 + (size_t)c * HID + k0);
        const int p  = k0 >> 5;
        const int kk = k0 & 31;
        const size_t dst = ((size_t)p * H4 + c) * 32 + kk;
        const float xs[4] = {v.x, v.y, v.z, v.w};
        ushort hv[4], lv[4];
#pragma unroll
        for (int j = 0; j < 4; j++) {
            const ushort h = f2bf(xs[j]);
            hv[j] = h;
            lv[j] = f2bf(xs[j] - __uint_as_float(((unsigned)h) << 16));
        }
        *(ushort4*)(W1h + dst) = make_ushort4(hv[0], hv[1], hv[2], hv[3]);
        *(ushort4*)(W1l + dst) = make_ushort4(lv[0], lv[1], lv[2], lv[3]);
    } else {
        const int e = blockIdx.x - 256;              // 0..63
        const int k0 = threadIdx.x * 4;              // 0..1020
        const float4 v = *(const float4*)(RW + (size_t)e * HID + k0);
        RWT[(size_t)(k0 + 0) * NEXP + e] = v.x;
        RWT[(size_t)(k0 + 1) * NEXP + e] = v.y;
        RWT[(size_t)(k0 + 2) * NEXP + e] = v.z;
        RWT[(size_t)(k0 + 3) * NEXP + e] = v.w;
    }
}

// ---------------------------------------------------------------------------
// Kernel 1: exact fp32 router-logits GEMM v5 — zero LDS, spill-proof.
// lane = token, wave owns 16 uniform cols (W via scalarizable uniform loads,
// 4-deep ring). X double-buffered in two STATICALLY-indexed tile buffers
// (v4's dynamic `cur` index caused scratch spill: 364 MB WRITE_SIZE, R5).
// ---------------------------------------------------------------------------
template<bool FULL>
__device__ __forceinline__ void tile16(const float4 (&xt)[4], int kb,
                                       const float* __restrict__ wbase,
                                       float4 (&wr)[4][4], float (&acc)[16])
{
#pragma unroll
    for (int kk = 0; kk < 16; kk++) {
        const int slot = kk & 3;                    // constant after unroll
        const float4 w0 = wr[slot][0], w1 = wr[slot][1];
        const float4 w2 = wr[slot][2], w3 = wr[slot][3];
        if (FULL || kk < 12) {                      // static guard
#pragma unroll
            for (int j = 0; j < 4; j++)
                wr[slot][j] = *(const float4*)(wbase + (size_t)(kb + kk + 4) * NEXP + j * 4);
        }
        const float4 xv4 = xt[kk >> 2];             // constant after unroll
        const float xv = (kk & 3) == 0 ? xv4.x : (kk & 3) == 1 ? xv4.y
                       : (kk & 3) == 2 ? xv4.z : xv4.w;
        acc[ 0] = fmaf(w0.x, xv, acc[ 0]); acc[ 1] = fmaf(w0.y, xv, acc[ 1]);
        acc[ 2] = fmaf(w0.z, xv, acc[ 2]); acc[ 3] = fmaf(w0.w, xv, acc[ 3]);
        acc[ 4] = fmaf(w1.x, xv, acc[ 4]); acc[ 5] = fmaf(w1.y, xv, acc[ 5]);
        acc[ 6] = fmaf(w1.z, xv, acc[ 6]); acc[ 7] = fmaf(w1.w, xv, acc[ 7]);
        acc[ 8] = fmaf(w2.x, xv, acc[ 8]); acc[ 9] = fmaf(w2.y, xv, acc[ 9]);
        acc[10] = fmaf(w2.z, xv, acc[10]); acc[11] = fmaf(w2.w, xv, acc[11]);
        acc[12] = fmaf(w3.x, xv, acc[12]); acc[13] = fmaf(w3.y, xv, acc[13]);
        acc[14] = fmaf(w3.z, xv, acc[14]); acc[15] = fmaf(w3.w, xv, acc[15]);
    }
}

__global__ __launch_bounds__(256) void logits_gemm(
    const float* __restrict__ X, const float* __restrict__ RWT,
    float* __restrict__ logits)
{
    const int tid  = threadIdx.x;
    const int lane = tid & 63;
    const int wave = tid >> 6;
    const int tok  = blockIdx.x * 64 + lane;
    const int colbase = __builtin_amdgcn_readfirstlane(wave * 16);

    const float* __restrict__ xrow  = X + (size_t)tok * HID;
    const float* __restrict__ wbase = RWT + colbase;

    float acc[16];
#pragma unroll
    for (int c = 0; c < 16; c++) acc[c] = 0.f;

    float4 xa[4], xb[4];     // two static tile buffers (no dynamic index!)
    float4 wr[4][4];         // W ring, 4 k deep

#pragma unroll
    for (int j = 0; j < 4; j++) xa[j] = *(const float4*)(xrow + j * 4);
#pragma unroll
    for (int d = 0; d < 4; d++)
#pragma unroll
        for (int j = 0; j < 4; j++)
            wr[d][j] = *(const float4*)(wbase + (size_t)d * NEXP + j * 4);

    // main: k0 = 0,32,...,960  (chunks [k0,k0+16) via xa, [k0+16,k0+32) via xb)
    for (int k0 = 0; k0 < HID - 32; k0 += 32) {
#pragma unroll
        for (int j = 0; j < 4; j++)
            xb[j] = *(const float4*)(xrow + k0 + 16 + j * 4);
        tile16<true>(xa, k0, wbase, wr, acc);
#pragma unroll
        for (int j = 0; j < 4; j++)
            xa[j] = *(const float4*)(xrow + k0 + 32 + j * 4);
        tile16<true>(xb, k0 + 16, wbase, wr, acc);
    }
    // peel k0 = 992: xa holds tile 992 (loaded in last main iter)
    {
#pragma unroll
        for (int j = 0; j < 4; j++)
            xb[j] = *(const float4*)(xrow + (HID - 16) + j * 4);
        tile16<true>(xa, HID - 32, wbase, wr, acc);      // refills max k=1011
        tile16<false>(xb, HID - 16, wbase, wr, acc);     // refill only kk<12
    }

#pragma unroll
    for (int j = 0; j < 4; j++) {
        float4 v = {acc[j * 4], acc[j * 4 + 1], acc[j * 4 + 2], acc[j * 4 + 3]};
        *(float4*)(logits + (size_t)tok * NEXP + colbase + j * 4) = v;
    }
}

// ---------------------------------------------------------------------------
// Kernel 2: complexity predictor via split-bf16 MFMA (unchanged, proven).
// ---------------------------------------------------------------------------
__global__ __launch_bounds__(256) void pred_mfma(
    const float* __restrict__ X,
    const ushort* __restrict__ W1h, const ushort* __restrict__ W1l,
    const float* __restrict__ B1, const float* __restrict__ W2,
    float* __restrict__ s2ws)
{
    __shared__ ushort Ah[4096];
    __shared__ ushort Al[4096];
    __shared__ ushort Bh[4096];
    __shared__ ushort Bl[4096];

    const int tid  = threadIdx.x;
    const int lane = tid & 63;
    const int wave = tid >> 6;
    const int wr = wave >> 1, wc = wave & 1;
    const int quad = lane >> 4, l15 = lane & 15;
    const int tok0 = blockIdx.x * 128;
    const int cb   = blockIdx.y;

    f32x4 acc[4][4];
#pragma unroll
    for (int fi = 0; fi < 4; fi++)
#pragma unroll
        for (int fj = 0; fj < 4; fj++) acc[fi][fj] = (f32x4){0.f, 0.f, 0.f, 0.f};

    float w2r[4], b1r[4];
#pragma unroll
    for (int f = 0; f < 4; f++) {
        const int col = cb * 128 + wc * 64 + f * 16 + l15;
        w2r[f] = W2[col];
        b1r[f] = B1[col];
    }

    for (int p = 0; p < 32; ++p) {
        const int k0 = p * 32;
        __syncthreads();

        {
            const size_t tile = ((size_t)p * H4 + cb * 128) * 32;
#pragma unroll
            for (int i = 0; i < 2; ++i) {
                const int j = i * 256 + tid;
                __builtin_amdgcn_global_load_lds(
                    (const __attribute__((address_space(1))) void*)(W1h + tile + (size_t)j * 8),
                    (__attribute__((address_space(3))) void*)((char*)Bh + (size_t)j * 16),
                    16, 0, 0);
                __builtin_amdgcn_global_load_lds(
                    (const __attribute__((address_space(1))) void*)(W1l + tile + (size_t)j * 8),
                    (__attribute__((address_space(3))) void*)((char*)Bl + (size_t)j * 16),
                    16, 0, 0);
            }
        }

#pragma unroll
        for (int it = 0; it < 4; ++it) {
            const int idx = it * 256 + tid;
            const int t   = idx >> 3;
            const int kc  = idx & 7;
            const float4 v = *(const float4*)(X + (size_t)(tok0 + t) * HID + k0 + kc * 4);
            const float xs[4] = {v.x, v.y, v.z, v.w};
            ushort hv[4], lv[4];
#pragma unroll
            for (int j = 0; j < 4; j++) {
                const ushort h = f2bf(xs[j]);
                hv[j] = h;
                lv[j] = f2bf(xs[j] - __uint_as_float(((unsigned)h) << 16));
            }
            const int a = t * 32 + kc * 4;
            *(ushort4*)&Ah[a] = make_ushort4(hv[0], hv[1], hv[2], hv[3]);
            *(ushort4*)&Al[a] = make_ushort4(lv[0], lv[1], lv[2], lv[3]);
        }
        __syncthreads();

        bf16x8 a_h[4], a_l[4], b_h[4], b_l[4];
#pragma unroll
        for (int f = 0; f < 4; ++f) {
            const int ra = (wr * 64 + f * 16 + l15) * 32 + quad * 8;
            const int rb = (wc * 64 + f * 16 + l15) * 32 + quad * 8;
            a_h[f] = *(const bf16x8*)&Ah[ra];
            a_l[f] = *(const bf16x8*)&Al[ra];
            b_h[f] = *(const bf16x8*)&Bh[rb];
            b_l[f] = *(const bf16x8*)&Bl[rb];
        }
#pragma unroll
        for (int fi = 0; fi < 4; ++fi)
#pragma unroll
            for (int fj = 0; fj < 4; ++fj) {
                acc[fi][fj] = __builtin_amdgcn_mfma_f32_16x16x32_bf16(a_h[fi], b_h[fj], acc[fi][fj], 0, 0, 0);
                acc[fi][fj] = __builtin_amdgcn_mfma_f32_16x16x32_bf16(a_l[fi], b_h[fj], acc[fi][fj], 0, 0, 0);
                acc[fi][fj] = __builtin_amdgcn_mfma_f32_16x16x32_bf16(a_h[fi], b_l[fj], acc[fi][fj], 0, 0, 0);
            }
    }

#pragma unroll
    for (int fi = 0; fi < 4; ++fi) {
#pragma unroll
        for (int r = 0; r < 4; ++r) {
            float s = 0.f;
#pragma unroll
            for (int fj = 0; fj < 4; ++fj) {
                const float hval = acc[fi][fj][r] + b1r[fj];
                s = fmaf(w2r[fj], fmaxf(hval, 0.f), s);
            }
            s += __shfl_xor(s, 1);
            s += __shfl_xor(s, 2);
            s += __shfl_xor(s, 4);
            s += __shfl_xor(s, 8);
            if (l15 == 0)
                atomicAdd(&s2ws[tok0 + wr * 64 + fi * 16 + quad * 4 + r], s);
        }
    }
}

// ---------------------------------------------------------------------------
// Kernel 3: per-token routing (unchanged, proven fast)
// ---------------------------------------------------------------------------
__global__ __launch_bounds__(64) void route_kernel(
    const float* __restrict__ logits, const float* __restrict__ s2ws,
    const float* __restrict__ B2, float* __restrict__ sel,
    float* __restrict__ wts, float* __restrict__ load_sum,
    float* __restrict__ ent_sum)
{
    const int lane = threadIdx.x;
    const int tok  = blockIdx.x * 64 + lane;

    float r[64];
    const float* lr = logits + (size_t)tok * NEXP;
#pragma unroll
    for (int e4 = 0; e4 < 16; e4++) {
        float4 v = *(const float4*)(lr + e4 * 4);
        r[e4 * 4 + 0] = v.x; r[e4 * 4 + 1] = v.y;
        r[e4 * 4 + 2] = v.z; r[e4 * 4 + 3] = v.w;
    }

    float v0 = -1e30f, v1 = -1e30f, v2 = -1e30f, v3 = -1e30f;
    int   i0 = 0, i1 = 0, i2 = 0, i3 = 0;
#pragma unroll
    for (int e = 0; e < 64; e++) {
        const float v = r[e];
        if (v > v3) {
            if (v > v2) {
                if (v > v1) {
                    if (v > v0) { v3=v2;i3=i2; v2=v1;i2=i1; v1=v0;i1=i0; v0=v;i0=e; }
                    else        { v3=v2;i3=i2; v2=v1;i2=i1; v1=v;i1=e; }
                } else          { v3=v2;i3=i2; v2=v;i2=e; }
            } else              { v3=v;i3=e; }
        }
    }

    const float s2 = s2ws[tok] + B2[0];
    const bool k4 = (s2 > 0.f);

    float w0, w1v, w2v, w3v;
    int   s1i, s2i, s3i;
    if (k4) {
        const float e0 = expf(v0 - v0), e1 = expf(v1 - v0);
        const float e2 = expf(v2 - v0), e3 = expf(v3 - v0);
        const float inv4 = 1.f / (e0 + e1 + e2 + e3);
        w0 = e0 * inv4; w1v = e1 * inv4; w2v = e2 * inv4; w3v = e3 * inv4;
        s1i = i1; s2i = i2; s3i = i3;
    } else {
        w0 = 1.f; w1v = 0.f; w2v = 0.f; w3v = 0.f;
        s1i = 0; s2i = 0; s3i = 0;
    }
    {
        float4 sv = {(float)i0, (float)s1i, (float)s2i, (float)s3i};
        float4 wv = {w0, w1v, w2v, w3v};
        *(float4*)(sel + (size_t)tok * 4) = sv;
        *(float4*)(wts + (size_t)tok * 4) = wv;
    }

    const float mx = v0;
    float S = 0.f, pz = 0.f;
#pragma unroll
    for (int e = 0; e < 64; e++) {
        const float z = r[e] - mx;
        const float t = expf(z);
        S += t; pz = fmaf(t, z, pz);
        r[e] = t;
    }
    const float inv = 1.f / S;
    float ent = logf(S) - pz * inv;

    float myload = 0.f;
#pragma unroll
    for (int e = 0; e < 64; e++) {
        float s = r[e] * inv;
        s += __shfl_xor(s, 1);
        s += __shfl_xor(s, 2);
        s += __shfl_xor(s, 4);
        s += __shfl_xor(s, 8);
        s += __shfl_xor(s, 16);
        s += __shfl_xor(s, 32);
        if (lane == e) myload = s;
    }
    atomicAdd(&load_sum[lane], myload);

    ent += __shfl_xor(ent, 1);
    ent += __shfl_xor(ent, 2);
    ent += __shfl_xor(ent, 4);
    ent += __shfl_xor(ent, 8);
    ent += __shfl_xor(ent, 16);
    ent += __shfl_xor(ent, 32);
    if (lane == 0) atomicAdd(ent_sum, ent);
}

__global__ void finalize_kernel(const float* __restrict__ load_sum,
                                const float* __restrict__ ent_sum,
                                float* __restrict__ out_scal)
{
    const int lane = threadIdx.x;
    const float le = load_sum[lane] * (1.f / (float)NTOK);
    float s = le;
#pragma unroll
    for (int o = 32; o >= 1; o >>= 1) s += __shfl_xor(s, o);
    const float mean = s * (1.f / 64.f);
    const float d = le - mean;
    float v = d * d;
#pragma unroll
    for (int o = 32; o >= 1; o >>= 1) v += __shfl_xor(v, o);
    if (lane == 0) {
        out_scal[0] = v * (1.f / 63.f);
        out_scal[1] = ent_sum[0] * (1.f / (float)NTOK);
    }
}

extern "C" void kernel_launch(void* const* d_in, const int* in_sizes, int n_in,
                              void* d_out, int out_size, void* d_ws, size_t ws_size,
                              hipStream_t stream) {
    const float* X  = (const float*)d_in[0];
    const float* RW = (const float*)d_in[1];
    const float* W1 = (const float*)d_in[2];
    const float* B1 = (const float*)d_in[3];
    const float* W2 = (const float*)d_in[4];
    const float* B2 = (const float*)d_in[5];

    float* out    = (float*)d_out;
    float* logits = out;
    float* sel    = out + (size_t)NTOK * NEXP;
    float* wts    = sel + (size_t)NTOK * 4;
    float* scal   = wts + (size_t)NTOK * 4;

    float* s2ws     = (float*)d_ws;                       // [32768]
    float* load_sum = s2ws + NTOK;                        // [64]
    float* ent_sum  = load_sum + 64;                      // [1]
    ushort* W1h = (ushort*)(s2ws + NTOK + 256);           // 512 KB
    ushort* W1l = W1h + (size_t)H4 * HID;                 // 512 KB
    float*  RWT = (float*)(W1l + (size_t)H4 * HID);       // 256 KB, [1024][64]

    hipMemsetAsync(d_ws, 0, (size_t)(NTOK + 65) * sizeof(float), stream);

    prep_kernel<<<320, 256, 0, stream>>>(W1, RW, W1h, W1l, RWT);
    logits_gemm<<<NTOK / 64, 256, 0, stream>>>(X, RWT, logits);
    pred_mfma<<<dim3(NTOK / 128, 2), 256, 0, stream>>>(X, W1h, W1l, B1, W2, s2ws);
    route_kernel<<<NTOK / 64, 64, 0, stream>>>(logits, s2ws, B2, sel, wts, load_sum, ent_sum);
    finalize_kernel<<<1, 64, 0, stream>>>(load_sum, ent_sum, scal);
}